// Round 1
// baseline (128.183 us; speedup 1.0000x reference)
//
#include <hip/hip_runtime.h>
#include <math.h>

// MatchNet: MLP(6->20->20->20->8, tanh) then 150-iter PDHG LP per row.
// One thread per batch row; all PDHG state in registers; A=[S;-I] sparsity
// hardcoded (S is a fixed structure matrix from the reference).
// tau = sigma = 1/||A||_F = 1/sqrt(28).

#define N_ITERS 150

__device__ __forceinline__ float fast_tanh(float a) {
    // tanh(a) = 1 - 2/(exp(2a)+1); saturates correctly for |a| large.
    float e = __expf(2.0f * a);
    return 1.0f - 2.0f / (e + 1.0f);
}

__global__ __launch_bounds__(64) void matchnet_kernel(
    const float* __restrict__ X,
    const float* __restrict__ W1, const float* __restrict__ b1,
    const float* __restrict__ W2, const float* __restrict__ b2,
    const float* __restrict__ W3, const float* __restrict__ b3,
    const float* __restrict__ W4, const float* __restrict__ b4,
    float* __restrict__ out, int B)
{
    __shared__ float sW1[120], sW2[400], sW3[400], sW4[160];
    __shared__ float sb1[20], sb2[20], sb3[20], sb4[8];
    for (int i = threadIdx.x; i < 120; i += blockDim.x) sW1[i] = W1[i];
    for (int i = threadIdx.x; i < 400; i += blockDim.x) sW2[i] = W2[i];
    for (int i = threadIdx.x; i < 400; i += blockDim.x) sW3[i] = W3[i];
    for (int i = threadIdx.x; i < 160; i += blockDim.x) sW4[i] = W4[i];
    if (threadIdx.x < 20) {
        sb1[threadIdx.x] = b1[threadIdx.x];
        sb2[threadIdx.x] = b2[threadIdx.x];
        sb3[threadIdx.x] = b3[threadIdx.x];
    }
    if (threadIdx.x < 8) sb4[threadIdx.x] = b4[threadIdx.x];
    __syncthreads();

    int row = blockIdx.x * blockDim.x + threadIdx.x;
    if (row >= B) return;

    // --- load bids (also the LP's b vector) ---
    float zin[6];
    #pragma unroll
    for (int i = 0; i < 6; i++) zin[i] = X[row * 6 + i];

    // --- MLP ---
    float h1[20], h2[20];
    #pragma unroll
    for (int j = 0; j < 20; j++) {
        float acc = sb1[j];
        #pragma unroll
        for (int i = 0; i < 6; i++) acc = fmaf(zin[i], sW1[i * 20 + j], acc);
        h1[j] = fast_tanh(acc);
    }
    #pragma unroll
    for (int j = 0; j < 20; j++) {
        float acc = sb2[j];
        #pragma unroll
        for (int i = 0; i < 20; i++) acc = fmaf(h1[i], sW2[i * 20 + j], acc);
        h2[j] = fast_tanh(acc);
    }
    #pragma unroll
    for (int j = 0; j < 20; j++) {
        float acc = sb3[j];
        #pragma unroll
        for (int i = 0; i < 20; i++) acc = fmaf(h2[i], sW3[i * 20 + j], acc);
        h1[j] = fast_tanh(acc);   // reuse h1 as h3
    }
    float z[8];
    #pragma unroll
    for (int k = 0; k < 8; k++) {
        float acc = sb4[k];
        #pragma unroll
        for (int i = 0; i < 20; i++) acc = fmaf(h1[i], sW4[i * 8 + k], acc);
        z[k] = acc;
    }

    // --- PDHG ---
    const float tau   = 0.18898223650461363f;  // 1/sqrt(28) = 1/||A||_F
    const float sigma = tau;
    const float tauC  = tau * 10.0f;           // tau * control_strength

    float x[8], xb[8], y[14];
    #pragma unroll
    for (int k = 0; k < 8; k++) { x[k] = fmaxf(z[k], 0.0f); xb[k] = x[k]; }
    #pragma unroll
    for (int j = 0; j < 14; j++) y[j] = 0.0f;

    #pragma unroll 1
    for (int it = 0; it < N_ITERS; it++) {
        // dual: y_j = max(0, y_j + sigma*(S_j . xbar - b_j)), S sparsity hardcoded
        float s0 = xb[0] + xb[2] + xb[5] + xb[7];
        float s1 = xb[1] + xb[3] + xb[4];
        float s2 = xb[0] + xb[1] + xb[6];
        float s3 = xb[2] + xb[3] + xb[5];
        float s4 = xb[1] + xb[2] + xb[4] + xb[7];
        float s5 = xb[0] + xb[4] + xb[6];
        y[0] = fmaxf(0.0f, fmaf(sigma, s0 - zin[0], y[0]));
        y[1] = fmaxf(0.0f, fmaf(sigma, s1 - zin[1], y[1]));
        y[2] = fmaxf(0.0f, fmaf(sigma, s2 - zin[2], y[2]));
        y[3] = fmaxf(0.0f, fmaf(sigma, s3 - zin[3], y[3]));
        y[4] = fmaxf(0.0f, fmaf(sigma, s4 - zin[4], y[4]));
        y[5] = fmaxf(0.0f, fmaf(sigma, s5 - zin[5], y[5]));
        // rows 6..13: A = -I, b = 0
        #pragma unroll
        for (int k = 0; k < 8; k++)
            y[6 + k] = fmaxf(0.0f, fmaf(-sigma, xb[k], y[6 + k]));

        // primal gradient: w_k = (y @ A)_k = sum_{j: S[j][k]=1} y_j - y_{6+k}
        float w0 = y[0] + y[2] + y[5] - y[6];
        float w1 = y[1] + y[2] + y[4] - y[7];
        float w2 = y[0] + y[3] + y[4] - y[8];
        float w3 = y[1] + y[3] - y[9];
        float w4 = y[1] + y[4] + y[5] - y[10];
        float w5 = y[0] + y[3] - y[11];
        float w6 = y[2] + y[5] - y[12];
        float w7 = y[0] + y[4] - y[13];
        float w[8] = {w0, w1, w2, w3, w4, w5, w6, w7};

        // prox: u = (x - tau*w) + tau; d = u - z; shrink toward z
        float d[8];
        float nsq0 = 0.0f, nsq1 = 0.0f;
        #pragma unroll
        for (int k = 0; k < 8; k++) {
            float u = fmaf(-tau, w[k], x[k]) + tau;
            d[k] = u - z[k];
            if (k & 1) nsq1 = fmaf(d[k], d[k], nsq1);
            else       nsq0 = fmaf(d[k], d[k], nsq0);
        }
        float n = sqrtf(nsq0 + nsq1);
        float scale = fmaxf(0.0f, 1.0f - tauC / fmaxf(n, 1e-12f));
        #pragma unroll
        for (int k = 0; k < 8; k++) {
            float xn = fmaf(scale, d[k], z[k]);
            xb[k] = fmaf(2.0f, xn, -x[k]);
            x[k] = xn;
        }
    }

    #pragma unroll
    for (int k = 0; k < 8; k++) out[row * 8 + k] = x[k];
}

extern "C" void kernel_launch(void* const* d_in, const int* in_sizes, int n_in,
                              void* d_out, int out_size, void* d_ws, size_t ws_size,
                              hipStream_t stream) {
    const float* X  = (const float*)d_in[0];
    const float* W1 = (const float*)d_in[1];
    const float* b1 = (const float*)d_in[2];
    const float* W2 = (const float*)d_in[3];
    const float* b2 = (const float*)d_in[4];
    const float* W3 = (const float*)d_in[5];
    const float* b3 = (const float*)d_in[6];
    const float* W4 = (const float*)d_in[7];
    const float* b4 = (const float*)d_in[8];
    float* out = (float*)d_out;

    int B = in_sizes[0] / 6;
    const int block = 64;
    int grid = (B + block - 1) / block;
    hipLaunchKernelGGL(matchnet_kernel, dim3(grid), dim3(block), 0, stream,
                       X, W1, b1, W2, b2, W3, b3, W4, b4, out, B);
}

// Round 2
// 116.717 us; speedup vs baseline: 1.0982x; 1.0982x over previous
//
#include <hip/hip_runtime.h>
#include <math.h>

// MatchNet: MLP(6->20->20->20->8, tanh) then 150-iter PDHG LP per row.
// One thread per batch row; PDHG state as explicit SCALARS (R1: compiler
// spilled array state to scratch at VGPR=36 -> 950 cyc/iter).
// __launch_bounds__(64,1): min 1 wave/EU so the allocator may use up to
// ~512 VGPRs — we only ever have 2 waves/CU resident, occupancy unaffected.
// A=[S;-I] sparsity hardcoded; tau = sigma = 1/||A||_F = 1/sqrt(28).
// Norm/shrink via v_rsq: scale = max(0, 1 - tauC*rsq(nsq)) — replaces
// sqrt + IEEE divide (~20 serial ops) with one trans op; nsq=0 gives
// rsq=+inf -> scale=0, same as the reference's 1e-12 clamp path.

#define N_ITERS 150

__device__ __forceinline__ float fast_tanh(float a) {
    // tanh(a) = 1 - 2/(exp(2a)+1); saturates correctly at +-1.
    float e = __expf(2.0f * a);
    return 1.0f - 2.0f * __builtin_amdgcn_rcpf(e + 1.0f);
}

__global__ __launch_bounds__(64, 1) void matchnet_kernel(
    const float* __restrict__ X,
    const float* __restrict__ W1, const float* __restrict__ b1,
    const float* __restrict__ W2, const float* __restrict__ b2,
    const float* __restrict__ W3, const float* __restrict__ b3,
    const float* __restrict__ W4, const float* __restrict__ b4,
    float* __restrict__ out, int B)
{
    __shared__ float sW1[120], sW2[400], sW3[400], sW4[160];
    __shared__ float sb1[20], sb2[20], sb3[20], sb4[8];
    for (int i = threadIdx.x; i < 120; i += blockDim.x) sW1[i] = W1[i];
    for (int i = threadIdx.x; i < 400; i += blockDim.x) sW2[i] = W2[i];
    for (int i = threadIdx.x; i < 400; i += blockDim.x) sW3[i] = W3[i];
    for (int i = threadIdx.x; i < 160; i += blockDim.x) sW4[i] = W4[i];
    if (threadIdx.x < 20) {
        sb1[threadIdx.x] = b1[threadIdx.x];
        sb2[threadIdx.x] = b2[threadIdx.x];
        sb3[threadIdx.x] = b3[threadIdx.x];
    }
    if (threadIdx.x < 8) sb4[threadIdx.x] = b4[threadIdx.x];
    __syncthreads();

    int row = blockIdx.x * blockDim.x + threadIdx.x;
    if (row >= B) return;

    // --- load bids (also the LP's b vector) ---
    float bb0 = X[row * 6 + 0], bb1 = X[row * 6 + 1], bb2 = X[row * 6 + 2];
    float bb3 = X[row * 6 + 3], bb4 = X[row * 6 + 4], bb5 = X[row * 6 + 5];

    // --- MLP (outside hot loop; arrays fine here) ---
    float h1[20], h2[20];
    #pragma unroll
    for (int j = 0; j < 20; j++) {
        float acc = sb1[j];
        acc = fmaf(bb0, sW1[0 * 20 + j], acc);
        acc = fmaf(bb1, sW1[1 * 20 + j], acc);
        acc = fmaf(bb2, sW1[2 * 20 + j], acc);
        acc = fmaf(bb3, sW1[3 * 20 + j], acc);
        acc = fmaf(bb4, sW1[4 * 20 + j], acc);
        acc = fmaf(bb5, sW1[5 * 20 + j], acc);
        h1[j] = fast_tanh(acc);
    }
    #pragma unroll
    for (int j = 0; j < 20; j++) {
        float acc = sb2[j];
        #pragma unroll
        for (int i = 0; i < 20; i++) acc = fmaf(h1[i], sW2[i * 20 + j], acc);
        h2[j] = fast_tanh(acc);
    }
    #pragma unroll
    for (int j = 0; j < 20; j++) {
        float acc = sb3[j];
        #pragma unroll
        for (int i = 0; i < 20; i++) acc = fmaf(h2[i], sW3[i * 20 + j], acc);
        h1[j] = fast_tanh(acc);   // reuse h1 as h3
    }
    float z0, z1, z2, z3, z4, z5, z6, z7;
    {
        float zt[8];
        #pragma unroll
        for (int k = 0; k < 8; k++) {
            float acc = sb4[k];
            #pragma unroll
            for (int i = 0; i < 20; i++) acc = fmaf(h1[i], sW4[i * 8 + k], acc);
            zt[k] = acc;
        }
        z0 = zt[0]; z1 = zt[1]; z2 = zt[2]; z3 = zt[3];
        z4 = zt[4]; z5 = zt[5]; z6 = zt[6]; z7 = zt[7];
    }

    // --- PDHG, all state in scalars ---
    const float tau   = 0.18898223650461363f;  // 1/sqrt(28)
    const float sigma = tau;
    const float tauC  = tau * 10.0f;           // tau * control_strength

    // loop-invariant: t_k = tau - z_k  (d = x - tau*w + tau - z)
    float t0 = tau - z0, t1 = tau - z1, t2 = tau - z2, t3 = tau - z3;
    float t4 = tau - z4, t5 = tau - z5, t6 = tau - z6, t7 = tau - z7;

    float x0 = fmaxf(z0, 0.0f), x1 = fmaxf(z1, 0.0f), x2 = fmaxf(z2, 0.0f), x3 = fmaxf(z3, 0.0f);
    float x4 = fmaxf(z4, 0.0f), x5 = fmaxf(z5, 0.0f), x6 = fmaxf(z6, 0.0f), x7 = fmaxf(z7, 0.0f);
    float xb0 = x0, xb1 = x1, xb2 = x2, xb3 = x3, xb4 = x4, xb5 = x5, xb6 = x6, xb7 = x7;
    float y0 = 0.0f, y1 = 0.0f, y2 = 0.0f, y3 = 0.0f, y4 = 0.0f, y5 = 0.0f;
    float y6 = 0.0f, y7 = 0.0f, y8 = 0.0f, y9 = 0.0f, y10 = 0.0f, y11 = 0.0f, y12 = 0.0f, y13 = 0.0f;

    #pragma unroll 1
    for (int it = 0; it < N_ITERS; it++) {
        // dual ascent on S-rows (sparsity hardcoded), then projection >= 0
        float s0 = (xb0 + xb2) + (xb5 + xb7);
        float s1 = (xb1 + xb3) + xb4;
        float s2 = (xb0 + xb1) + xb6;
        float s3 = (xb2 + xb3) + xb5;
        float s4 = (xb1 + xb2) + (xb4 + xb7);
        float s5 = (xb0 + xb4) + xb6;
        y0 = fmaxf(0.0f, fmaf(sigma, s0 - bb0, y0));
        y1 = fmaxf(0.0f, fmaf(sigma, s1 - bb1, y1));
        y2 = fmaxf(0.0f, fmaf(sigma, s2 - bb2, y2));
        y3 = fmaxf(0.0f, fmaf(sigma, s3 - bb3, y3));
        y4 = fmaxf(0.0f, fmaf(sigma, s4 - bb4, y4));
        y5 = fmaxf(0.0f, fmaf(sigma, s5 - bb5, y5));
        // rows 6..13: A = -I, b = 0
        y6  = fmaxf(0.0f, fmaf(-sigma, xb0, y6));
        y7  = fmaxf(0.0f, fmaf(-sigma, xb1, y7));
        y8  = fmaxf(0.0f, fmaf(-sigma, xb2, y8));
        y9  = fmaxf(0.0f, fmaf(-sigma, xb3, y9));
        y10 = fmaxf(0.0f, fmaf(-sigma, xb4, y10));
        y11 = fmaxf(0.0f, fmaf(-sigma, xb5, y11));
        y12 = fmaxf(0.0f, fmaf(-sigma, xb6, y12));
        y13 = fmaxf(0.0f, fmaf(-sigma, xb7, y13));

        // w_k = (y @ A)_k = sum_{j: S[j][k]=1} y_j - y_{6+k}
        float w0 = (y0 + y2) + (y5 - y6);
        float w1 = (y1 + y2) + (y4 - y7);
        float w2 = (y0 + y3) + (y4 - y8);
        float w3 = (y1 + y3) - y9;
        float w4 = (y1 + y4) + (y5 - y10);
        float w5 = (y0 + y3) - y11;
        float w6 = (y2 + y5) - y12;
        float w7 = (y0 + y4) - y13;

        // d_k = (x_k + t_k) - tau*w_k
        float d0 = fmaf(-tau, w0, x0 + t0);
        float d1 = fmaf(-tau, w1, x1 + t1);
        float d2 = fmaf(-tau, w2, x2 + t2);
        float d3 = fmaf(-tau, w3, x3 + t3);
        float d4 = fmaf(-tau, w4, x4 + t4);
        float d5 = fmaf(-tau, w5, x5 + t5);
        float d6 = fmaf(-tau, w6, x6 + t6);
        float d7 = fmaf(-tau, w7, x7 + t7);

        // ||d||^2 via balanced fma tree
        float na = fmaf(d1, d1, d0 * d0);
        float nb = fmaf(d3, d3, d2 * d2);
        float nc = fmaf(d5, d5, d4 * d4);
        float nd = fmaf(d7, d7, d6 * d6);
        float nsq = (na + nb) + (nc + nd);

        // scale = max(0, 1 - tauC/||d||) ; rsq(0)=inf -> scale=0 (matches ref clamp)
        float rs = __builtin_amdgcn_rsqf(nsq);
        float scale = fmaxf(0.0f, fmaf(-tauC, rs, 1.0f));

        float xn;
        xn = fmaf(scale, d0, z0); xb0 = fmaf(2.0f, xn, -x0); x0 = xn;
        xn = fmaf(scale, d1, z1); xb1 = fmaf(2.0f, xn, -x1); x1 = xn;
        xn = fmaf(scale, d2, z2); xb2 = fmaf(2.0f, xn, -x2); x2 = xn;
        xn = fmaf(scale, d3, z3); xb3 = fmaf(2.0f, xn, -x3); x3 = xn;
        xn = fmaf(scale, d4, z4); xb4 = fmaf(2.0f, xn, -x4); x4 = xn;
        xn = fmaf(scale, d5, z5); xb5 = fmaf(2.0f, xn, -x5); x5 = xn;
        xn = fmaf(scale, d6, z6); xb6 = fmaf(2.0f, xn, -x6); x6 = xn;
        xn = fmaf(scale, d7, z7); xb7 = fmaf(2.0f, xn, -x7); x7 = xn;
    }

    float4* out4 = (float4*)out;
    out4[row * 2 + 0] = make_float4(x0, x1, x2, x3);
    out4[row * 2 + 1] = make_float4(x4, x5, x6, x7);
}

extern "C" void kernel_launch(void* const* d_in, const int* in_sizes, int n_in,
                              void* d_out, int out_size, void* d_ws, size_t ws_size,
                              hipStream_t stream) {
    const float* X  = (const float*)d_in[0];
    const float* W1 = (const float*)d_in[1];
    const float* b1 = (const float*)d_in[2];
    const float* W2 = (const float*)d_in[3];
    const float* b2 = (const float*)d_in[4];
    const float* W3 = (const float*)d_in[5];
    const float* b3 = (const float*)d_in[6];
    const float* W4 = (const float*)d_in[7];
    const float* b4 = (const float*)d_in[8];
    float* out = (float*)d_out;

    int B = in_sizes[0] / 6;
    const int block = 64;
    int grid = (B + block - 1) / block;
    hipLaunchKernelGGL(matchnet_kernel, dim3(grid), dim3(block), 0, stream,
                       X, W1, b1, W2, b2, W3, b3, W4, b4, out, B);
}

// Round 3
// 116.592 us; speedup vs baseline: 1.0994x; 1.0011x over previous
//
#include <hip/hip_runtime.h>
#include <math.h>

// MatchNet: MLP(6->20->20->20->8, tanh) then 150-iter PDHG LP per row.
// One thread per batch row; PDHG state in scalars.
// R2 post-mortem: VGPR=52 == exact live set; 775 cyc/iter vs 214 issue
// -> scheduler serialized the independent chains to hit a low reg tier.
// amdgpu_waves_per_eu(1,1) pins the occupancy target to 1 wave/EU so the
// backend schedules for ILP with the full 512-VGPR budget (we only have
// 0.5 waves/SIMD resident anyway - occupancy loss is zero).
// A=[S;-I] sparsity hardcoded; tau = sigma = 1/||A||_F = 1/sqrt(28).
// scale = max(0, 1 - tauC*rsq(nsq)): rsq(0)=inf -> scale=0 matches the
// reference's 1e-12 clamp path.

#define N_ITERS 150

__device__ __forceinline__ float fast_tanh(float a) {
    // tanh(a) = 1 - 2/(exp(2a)+1); saturates correctly at +-1.
    float e = __expf(2.0f * a);
    return 1.0f - 2.0f * __builtin_amdgcn_rcpf(e + 1.0f);
}

__global__ void __launch_bounds__(64)
__attribute__((amdgpu_waves_per_eu(1, 1)))
matchnet_kernel(
    const float* __restrict__ X,
    const float* __restrict__ W1, const float* __restrict__ b1,
    const float* __restrict__ W2, const float* __restrict__ b2,
    const float* __restrict__ W3, const float* __restrict__ b3,
    const float* __restrict__ W4, const float* __restrict__ b4,
    float* __restrict__ out, int B)
{
    __shared__ float sW1[120], sW2[400], sW3[400], sW4[160];
    __shared__ float sb1[20], sb2[20], sb3[20], sb4[8];
    for (int i = threadIdx.x; i < 120; i += blockDim.x) sW1[i] = W1[i];
    for (int i = threadIdx.x; i < 400; i += blockDim.x) sW2[i] = W2[i];
    for (int i = threadIdx.x; i < 400; i += blockDim.x) sW3[i] = W3[i];
    for (int i = threadIdx.x; i < 160; i += blockDim.x) sW4[i] = W4[i];
    if (threadIdx.x < 20) {
        sb1[threadIdx.x] = b1[threadIdx.x];
        sb2[threadIdx.x] = b2[threadIdx.x];
        sb3[threadIdx.x] = b3[threadIdx.x];
    }
    if (threadIdx.x < 8) sb4[threadIdx.x] = b4[threadIdx.x];
    __syncthreads();

    int row = blockIdx.x * blockDim.x + threadIdx.x;
    if (row >= B) return;

    // --- load bids (also the LP's b vector) ---
    float bb0 = X[row * 6 + 0], bb1 = X[row * 6 + 1], bb2 = X[row * 6 + 2];
    float bb3 = X[row * 6 + 3], bb4 = X[row * 6 + 4], bb5 = X[row * 6 + 5];

    // --- MLP (outside hot loop) ---
    float h1[20], h2[20];
    #pragma unroll
    for (int j = 0; j < 20; j++) {
        float acc = sb1[j];
        acc = fmaf(bb0, sW1[0 * 20 + j], acc);
        acc = fmaf(bb1, sW1[1 * 20 + j], acc);
        acc = fmaf(bb2, sW1[2 * 20 + j], acc);
        acc = fmaf(bb3, sW1[3 * 20 + j], acc);
        acc = fmaf(bb4, sW1[4 * 20 + j], acc);
        acc = fmaf(bb5, sW1[5 * 20 + j], acc);
        h1[j] = fast_tanh(acc);
    }
    #pragma unroll
    for (int j = 0; j < 20; j++) {
        float acc = sb2[j];
        #pragma unroll
        for (int i = 0; i < 20; i++) acc = fmaf(h1[i], sW2[i * 20 + j], acc);
        h2[j] = fast_tanh(acc);
    }
    #pragma unroll
    for (int j = 0; j < 20; j++) {
        float acc = sb3[j];
        #pragma unroll
        for (int i = 0; i < 20; i++) acc = fmaf(h2[i], sW3[i * 20 + j], acc);
        h1[j] = fast_tanh(acc);   // reuse h1 as h3
    }
    float z0, z1, z2, z3, z4, z5, z6, z7;
    {
        float zt[8];
        #pragma unroll
        for (int k = 0; k < 8; k++) {
            float acc = sb4[k];
            #pragma unroll
            for (int i = 0; i < 20; i++) acc = fmaf(h1[i], sW4[i * 8 + k], acc);
            zt[k] = acc;
        }
        z0 = zt[0]; z1 = zt[1]; z2 = zt[2]; z3 = zt[3];
        z4 = zt[4]; z5 = zt[5]; z6 = zt[6]; z7 = zt[7];
    }

    // --- PDHG, all state in scalars ---
    const float tau   = 0.18898223650461363f;  // 1/sqrt(28)
    const float sigma = tau;
    const float tauC  = tau * 10.0f;           // tau * control_strength

    // loop-invariant: t_k = tau - z_k  (d = x - tau*w + tau - z)
    float t0 = tau - z0, t1 = tau - z1, t2 = tau - z2, t3 = tau - z3;
    float t4 = tau - z4, t5 = tau - z5, t6 = tau - z6, t7 = tau - z7;

    float x0 = fmaxf(z0, 0.0f), x1 = fmaxf(z1, 0.0f), x2 = fmaxf(z2, 0.0f), x3 = fmaxf(z3, 0.0f);
    float x4 = fmaxf(z4, 0.0f), x5 = fmaxf(z5, 0.0f), x6 = fmaxf(z6, 0.0f), x7 = fmaxf(z7, 0.0f);
    float xb0 = x0, xb1 = x1, xb2 = x2, xb3 = x3, xb4 = x4, xb5 = x5, xb6 = x6, xb7 = x7;
    float y0 = 0.0f, y1 = 0.0f, y2 = 0.0f, y3 = 0.0f, y4 = 0.0f, y5 = 0.0f;
    float y6 = 0.0f, y7 = 0.0f, y8 = 0.0f, y9 = 0.0f, y10 = 0.0f, y11 = 0.0f, y12 = 0.0f, y13 = 0.0f;

    #pragma unroll 1
    for (int it = 0; it < N_ITERS; it++) {
        // dual ascent on S-rows (sparsity hardcoded), then projection >= 0
        float s0 = (xb0 + xb2) + (xb5 + xb7);
        float s1 = (xb1 + xb3) + xb4;
        float s2 = (xb0 + xb1) + xb6;
        float s3 = (xb2 + xb3) + xb5;
        float s4 = (xb1 + xb2) + (xb4 + xb7);
        float s5 = (xb0 + xb4) + xb6;
        y0 = fmaxf(0.0f, fmaf(sigma, s0 - bb0, y0));
        y1 = fmaxf(0.0f, fmaf(sigma, s1 - bb1, y1));
        y2 = fmaxf(0.0f, fmaf(sigma, s2 - bb2, y2));
        y3 = fmaxf(0.0f, fmaf(sigma, s3 - bb3, y3));
        y4 = fmaxf(0.0f, fmaf(sigma, s4 - bb4, y4));
        y5 = fmaxf(0.0f, fmaf(sigma, s5 - bb5, y5));
        // rows 6..13: A = -I, b = 0
        y6  = fmaxf(0.0f, fmaf(-sigma, xb0, y6));
        y7  = fmaxf(0.0f, fmaf(-sigma, xb1, y7));
        y8  = fmaxf(0.0f, fmaf(-sigma, xb2, y8));
        y9  = fmaxf(0.0f, fmaf(-sigma, xb3, y9));
        y10 = fmaxf(0.0f, fmaf(-sigma, xb4, y10));
        y11 = fmaxf(0.0f, fmaf(-sigma, xb5, y11));
        y12 = fmaxf(0.0f, fmaf(-sigma, xb6, y12));
        y13 = fmaxf(0.0f, fmaf(-sigma, xb7, y13));

        // w_k = (y @ A)_k = sum_{j: S[j][k]=1} y_j - y_{6+k}
        float w0 = (y0 + y2) + (y5 - y6);
        float w1 = (y1 + y2) + (y4 - y7);
        float w2 = (y0 + y3) + (y4 - y8);
        float w3 = (y1 + y3) - y9;
        float w4 = (y1 + y4) + (y5 - y10);
        float w5 = (y0 + y3) - y11;
        float w6 = (y2 + y5) - y12;
        float w7 = (y0 + y4) - y13;

        // d_k = (x_k + t_k) - tau*w_k
        float d0 = fmaf(-tau, w0, x0 + t0);
        float d1 = fmaf(-tau, w1, x1 + t1);
        float d2 = fmaf(-tau, w2, x2 + t2);
        float d3 = fmaf(-tau, w3, x3 + t3);
        float d4 = fmaf(-tau, w4, x4 + t4);
        float d5 = fmaf(-tau, w5, x5 + t5);
        float d6 = fmaf(-tau, w6, x6 + t6);
        float d7 = fmaf(-tau, w7, x7 + t7);

        // ||d||^2 via balanced fma tree
        float na = fmaf(d1, d1, d0 * d0);
        float nb = fmaf(d3, d3, d2 * d2);
        float nc = fmaf(d5, d5, d4 * d4);
        float nd = fmaf(d7, d7, d6 * d6);
        float nsq = (na + nb) + (nc + nd);

        // scale = max(0, 1 - tauC/||d||) ; rsq(0)=inf -> scale=0 (matches ref clamp)
        float rs = __builtin_amdgcn_rsqf(nsq);
        float scale = fmaxf(0.0f, fmaf(-tauC, rs, 1.0f));

        float xn0 = fmaf(scale, d0, z0);
        float xn1 = fmaf(scale, d1, z1);
        float xn2 = fmaf(scale, d2, z2);
        float xn3 = fmaf(scale, d3, z3);
        float xn4 = fmaf(scale, d4, z4);
        float xn5 = fmaf(scale, d5, z5);
        float xn6 = fmaf(scale, d6, z6);
        float xn7 = fmaf(scale, d7, z7);
        xb0 = fmaf(2.0f, xn0, -x0); x0 = xn0;
        xb1 = fmaf(2.0f, xn1, -x1); x1 = xn1;
        xb2 = fmaf(2.0f, xn2, -x2); x2 = xn2;
        xb3 = fmaf(2.0f, xn3, -x3); x3 = xn3;
        xb4 = fmaf(2.0f, xn4, -x4); x4 = xn4;
        xb5 = fmaf(2.0f, xn5, -x5); x5 = xn5;
        xb6 = fmaf(2.0f, xn6, -x6); x6 = xn6;
        xb7 = fmaf(2.0f, xn7, -x7); x7 = xn7;
    }

    float4* out4 = (float4*)out;
    out4[row * 2 + 0] = make_float4(x0, x1, x2, x3);
    out4[row * 2 + 1] = make_float4(x4, x5, x6, x7);
}

extern "C" void kernel_launch(void* const* d_in, const int* in_sizes, int n_in,
                              void* d_out, int out_size, void* d_ws, size_t ws_size,
                              hipStream_t stream) {
    const float* X  = (const float*)d_in[0];
    const float* W1 = (const float*)d_in[1];
    const float* b1 = (const float*)d_in[2];
    const float* W2 = (const float*)d_in[3];
    const float* b2 = (const float*)d_in[4];
    const float* W3 = (const float*)d_in[5];
    const float* b3 = (const float*)d_in[6];
    const float* W4 = (const float*)d_in[7];
    const float* b4 = (const float*)d_in[8];
    float* out = (float*)d_out;

    int B = in_sizes[0] / 6;
    const int block = 64;
    int grid = (B + block - 1) / block;
    hipLaunchKernelGGL(matchnet_kernel, dim3(grid), dim3(block), 0, stream,
                       X, W1, b1, W2, b2, W3, b3, W4, b4, out, B);
}

// Round 4
// 115.402 us; speedup vs baseline: 1.1108x; 1.0103x over previous
//
#include <hip/hip_runtime.h>
#include <math.h>

// MatchNet: MLP(6->20->20->20->8, tanh) then 150-iter PDHG LP per row.
// One thread per batch row; PDHG state in scalars.
//
// R3 post-mortem: VALUBusy*cyc/iter == 2*instcount across R1-R3 =>
// backend emits the loop in dependency order; in-order wave stalls
// ~6.8 cyc on EVERY op (dep latency), ILP unused. Fix: pin a hand
// schedule — dependency-LEVEL groups of independent ops separated by
// __builtin_amdgcn_sched_barrier(0). No memory ops in the loop, so
// order-pinning can't cause waitcnt spam.
//
// Algebra: duals scaled by tau (Y = tau*y, c = tau*sigma = 1/28) kills
// the 8 tau*w fmas; s/col sums CSE'd. d = (x+t) + YI - col.
// scale = max(0, 1 - tauC*rsq(nsq)); rsq(0)=inf -> scale=0 == ref clamp.

#define N_ITERS 150
#define LEVEL() __builtin_amdgcn_sched_barrier(0)

__device__ __forceinline__ float fast_tanh(float a) {
    float e = __expf(2.0f * a);
    return 1.0f - 2.0f * __builtin_amdgcn_rcpf(e + 1.0f);
}

__global__ void __launch_bounds__(64)
__attribute__((amdgpu_waves_per_eu(1, 1)))
matchnet_kernel(
    const float* __restrict__ X,
    const float* __restrict__ W1, const float* __restrict__ b1,
    const float* __restrict__ W2, const float* __restrict__ b2,
    const float* __restrict__ W3, const float* __restrict__ b3,
    const float* __restrict__ W4, const float* __restrict__ b4,
    float* __restrict__ out, int B)
{
    __shared__ float sW1[120], sW2[400], sW3[400], sW4[160];
    __shared__ float sb1[20], sb2[20], sb3[20], sb4[8];
    for (int i = threadIdx.x; i < 120; i += blockDim.x) sW1[i] = W1[i];
    for (int i = threadIdx.x; i < 400; i += blockDim.x) sW2[i] = W2[i];
    for (int i = threadIdx.x; i < 400; i += blockDim.x) sW3[i] = W3[i];
    for (int i = threadIdx.x; i < 160; i += blockDim.x) sW4[i] = W4[i];
    if (threadIdx.x < 20) {
        sb1[threadIdx.x] = b1[threadIdx.x];
        sb2[threadIdx.x] = b2[threadIdx.x];
        sb3[threadIdx.x] = b3[threadIdx.x];
    }
    if (threadIdx.x < 8) sb4[threadIdx.x] = b4[threadIdx.x];
    __syncthreads();

    int row = blockIdx.x * blockDim.x + threadIdx.x;
    if (row >= B) return;

    float bb0 = X[row * 6 + 0], bb1 = X[row * 6 + 1], bb2 = X[row * 6 + 2];
    float bb3 = X[row * 6 + 3], bb4 = X[row * 6 + 4], bb5 = X[row * 6 + 5];

    // --- MLP ---
    float h1[20], h2[20];
    #pragma unroll
    for (int j = 0; j < 20; j++) {
        float acc = sb1[j];
        acc = fmaf(bb0, sW1[0 * 20 + j], acc);
        acc = fmaf(bb1, sW1[1 * 20 + j], acc);
        acc = fmaf(bb2, sW1[2 * 20 + j], acc);
        acc = fmaf(bb3, sW1[3 * 20 + j], acc);
        acc = fmaf(bb4, sW1[4 * 20 + j], acc);
        acc = fmaf(bb5, sW1[5 * 20 + j], acc);
        h1[j] = fast_tanh(acc);
    }
    #pragma unroll
    for (int j = 0; j < 20; j++) {
        float acc = sb2[j];
        #pragma unroll
        for (int i = 0; i < 20; i++) acc = fmaf(h1[i], sW2[i * 20 + j], acc);
        h2[j] = fast_tanh(acc);
    }
    #pragma unroll
    for (int j = 0; j < 20; j++) {
        float acc = sb3[j];
        #pragma unroll
        for (int i = 0; i < 20; i++) acc = fmaf(h2[i], sW3[i * 20 + j], acc);
        h1[j] = fast_tanh(acc);   // reuse h1 as h3
    }
    float z0, z1, z2, z3, z4, z5, z6, z7;
    {
        float zt[8];
        #pragma unroll
        for (int k = 0; k < 8; k++) {
            float acc = sb4[k];
            #pragma unroll
            for (int i = 0; i < 20; i++) acc = fmaf(h1[i], sW4[i * 8 + k], acc);
            zt[k] = acc;
        }
        z0 = zt[0]; z1 = zt[1]; z2 = zt[2]; z3 = zt[3];
        z4 = zt[4]; z5 = zt[5]; z6 = zt[6]; z7 = zt[7];
    }

    // --- PDHG constants / invariants ---
    const float tau  = 0.18898223650461363f;   // 1/sqrt(28)
    const float c    = 0.03571428571428571f;   // tau*sigma = 1/28
    const float tauC = 1.8898223650461363f;    // tau * control_strength(10)

    float t0 = tau - z0, t1 = tau - z1, t2 = tau - z2, t3 = tau - z3;
    float t4 = tau - z4, t5 = tau - z5, t6 = tau - z6, t7 = tau - z7;
    float cb0 = c * bb0, cb1 = c * bb1, cb2 = c * bb2;
    float cb3 = c * bb3, cb4 = c * bb4, cb5 = c * bb5;

    float x0 = fmaxf(z0, 0.0f), x1 = fmaxf(z1, 0.0f), x2 = fmaxf(z2, 0.0f), x3 = fmaxf(z3, 0.0f);
    float x4 = fmaxf(z4, 0.0f), x5 = fmaxf(z5, 0.0f), x6 = fmaxf(z6, 0.0f), x7 = fmaxf(z7, 0.0f);
    float xb0 = x0, xb1 = x1, xb2 = x2, xb3 = x3, xb4 = x4, xb5 = x5, xb6 = x6, xb7 = x7;
    // scaled duals: YS_j = tau*y_j (S rows), YI_k = tau*y_{6+k} (-I rows)
    float YS0 = 0.0f, YS1 = 0.0f, YS2 = 0.0f, YS3 = 0.0f, YS4 = 0.0f, YS5 = 0.0f;
    float YI0 = 0.0f, YI1 = 0.0f, YI2 = 0.0f, YI3 = 0.0f;
    float YI4 = 0.0f, YI5 = 0.0f, YI6 = 0.0f, YI7 = 0.0f;

    #pragma unroll 1
    for (int it = 0; it < N_ITERS; it++) {
        // ---- L1: s-pairs, I-dual fmas, e = x + t  (23 independent ops)
        float p02 = xb0 + xb2, p57 = xb5 + xb7, p13 = xb1 + xb3;
        float p23 = xb2 + xb3, p12 = xb1 + xb2, p47 = xb4 + xb7;
        float p06 = xb0 + xb6;
        float u0 = fmaf(-c, xb0, YI0), u1 = fmaf(-c, xb1, YI1);
        float u2 = fmaf(-c, xb2, YI2), u3 = fmaf(-c, xb3, YI3);
        float u4 = fmaf(-c, xb4, YI4), u5 = fmaf(-c, xb5, YI5);
        float u6 = fmaf(-c, xb6, YI6), u7 = fmaf(-c, xb7, YI7);
        float e0 = x0 + t0, e1 = x1 + t1, e2 = x2 + t2, e3 = x3 + t3;
        float e4 = x4 + t4, e5 = x5 + t5, e6 = x6 + t6, e7 = x7 + t7;
        LEVEL();
        // ---- L2: s sums, YI projection  (14)
        float s0 = p02 + p57, s1 = p13 + xb4, s2 = p06 + xb1;
        float s3 = p23 + xb5, s4 = p12 + p47, s5 = p06 + xb4;
        YI0 = fmaxf(0.0f, u0); YI1 = fmaxf(0.0f, u1);
        YI2 = fmaxf(0.0f, u2); YI3 = fmaxf(0.0f, u3);
        YI4 = fmaxf(0.0f, u4); YI5 = fmaxf(0.0f, u5);
        YI6 = fmaxf(0.0f, u6); YI7 = fmaxf(0.0f, u7);
        LEVEL();
        // ---- L3: S-dual fmas, dA = e + YI  (14)
        float v0 = fmaf(c, s0, YS0), v1 = fmaf(c, s1, YS1);
        float v2 = fmaf(c, s2, YS2), v3 = fmaf(c, s3, YS3);
        float v4 = fmaf(c, s4, YS4), v5 = fmaf(c, s5, YS5);
        float dA0 = e0 + YI0, dA1 = e1 + YI1, dA2 = e2 + YI2, dA3 = e3 + YI3;
        float dA4 = e4 + YI4, dA5 = e5 + YI5, dA6 = e6 + YI6, dA7 = e7 + YI7;
        LEVEL();
        // ---- L4: subtract c*b  (6)
        v0 -= cb0; v1 -= cb1; v2 -= cb2; v3 -= cb3; v4 -= cb4; v5 -= cb5;
        LEVEL();
        // ---- L5: YS projection  (6)
        YS0 = fmaxf(0.0f, v0); YS1 = fmaxf(0.0f, v1); YS2 = fmaxf(0.0f, v2);
        YS3 = fmaxf(0.0f, v3); YS4 = fmaxf(0.0f, v4); YS5 = fmaxf(0.0f, v5);
        LEVEL();
        // ---- L6: column-sum pairs  (5)
        float r03 = YS0 + YS3, r25 = YS2 + YS5, r14 = YS1 + YS4;
        float c3 = YS1 + YS3, c7 = YS0 + YS4;
        LEVEL();
        // ---- L7: full column sums  (4)   col5=r03, col6=r25
        float c0 = YS0 + r25, c1 = r14 + YS2, c2 = r03 + YS4, c4 = r14 + YS5;
        LEVEL();
        // ---- L8: d = dA - col  (8)
        float d0 = dA0 - c0, d1 = dA1 - c1, d2 = dA2 - c2, d3 = dA3 - c3;
        float d4 = dA4 - c4, d5 = dA5 - r03, d6 = dA6 - r25, d7 = dA7 - c7;
        LEVEL();
        // ---- L9..L12: nsq tree  (4+4+2+1)
        float m0 = d0 * d0, m2 = d2 * d2, m4 = d4 * d4, m6 = d6 * d6;
        LEVEL();
        float na = fmaf(d1, d1, m0), nb = fmaf(d3, d3, m2);
        float nc = fmaf(d5, d5, m4), nd = fmaf(d7, d7, m6);
        LEVEL();
        float nab = na + nb, ncd = nc + nd;
        LEVEL();
        float nsq = nab + ncd;
        LEVEL();
        // ---- L13..L15: scale  (3)
        float rs = __builtin_amdgcn_rsqf(nsq);
        LEVEL();
        float sc = fmaf(-tauC, rs, 1.0f);
        LEVEL();
        float scale = fmaxf(0.0f, sc);
        LEVEL();
        // ---- L16: xn  (8)
        float xn0 = fmaf(scale, d0, z0), xn1 = fmaf(scale, d1, z1);
        float xn2 = fmaf(scale, d2, z2), xn3 = fmaf(scale, d3, z3);
        float xn4 = fmaf(scale, d4, z4), xn5 = fmaf(scale, d5, z5);
        float xn6 = fmaf(scale, d6, z6), xn7 = fmaf(scale, d7, z7);
        LEVEL();
        // ---- L17: xb, commit x  (8)
        xb0 = fmaf(2.0f, xn0, -x0); x0 = xn0;
        xb1 = fmaf(2.0f, xn1, -x1); x1 = xn1;
        xb2 = fmaf(2.0f, xn2, -x2); x2 = xn2;
        xb3 = fmaf(2.0f, xn3, -x3); x3 = xn3;
        xb4 = fmaf(2.0f, xn4, -x4); x4 = xn4;
        xb5 = fmaf(2.0f, xn5, -x5); x5 = xn5;
        xb6 = fmaf(2.0f, xn6, -x6); x6 = xn6;
        xb7 = fmaf(2.0f, xn7, -x7); x7 = xn7;
        LEVEL();
    }

    float4* out4 = (float4*)out;
    out4[row * 2 + 0] = make_float4(x0, x1, x2, x3);
    out4[row * 2 + 1] = make_float4(x4, x5, x6, x7);
}

extern "C" void kernel_launch(void* const* d_in, const int* in_sizes, int n_in,
                              void* d_out, int out_size, void* d_ws, size_t ws_size,
                              hipStream_t stream) {
    const float* X  = (const float*)d_in[0];
    const float* W1 = (const float*)d_in[1];
    const float* b1 = (const float*)d_in[2];
    const float* W2 = (const float*)d_in[3];
    const float* b2 = (const float*)d_in[4];
    const float* W3 = (const float*)d_in[5];
    const float* b3 = (const float*)d_in[6];
    const float* W4 = (const float*)d_in[7];
    const float* b4 = (const float*)d_in[8];
    float* out = (float*)d_out;

    int B = in_sizes[0] / 6;
    const int block = 64;
    int grid = (B + block - 1) / block;
    hipLaunchKernelGGL(matchnet_kernel, dim3(grid), dim3(block), 0, stream,
                       X, W1, b1, W2, b2, W3, b3, W4, b4, out, B);
}

// Round 5
// 105.972 us; speedup vs baseline: 1.2096x; 1.0890x over previous
//
#include <hip/hip_runtime.h>
#include <math.h>

// MatchNet: MLP(6->20->20->20->8, tanh) then 150-iter PDHG LP per row.
// One thread per row. R2-R4 post-mortem: per-iter cost is SCHEDULE-INVARIANT
// (~740 cyc/iter for ~110 VALU insts across serial/leveled schedules and
// 52/132 VGPR budgets) => per-wave issue cadence floor (or downclock);
// either way wall time ~ insts/iter. Lever: packed FP32 (v_pk_*_f32,
// CDNA2+ dual-FP32) — float2 ext_vector ops halve the regular 8-wide
// chains; irregular S/col sums stay scalar. MLP: pair accumulators +
// b128 LDS weight reads.

#define N_ITERS 150
typedef float f2 __attribute__((ext_vector_type(2)));
typedef float f4 __attribute__((ext_vector_type(4)));

__device__ __forceinline__ float fast_tanh(float a) {
    float e = __expf(2.0f * a);
    return 1.0f - 2.0f * __builtin_amdgcn_rcpf(e + 1.0f);
}
__device__ __forceinline__ f2 max0(f2 a) {
    return f2{fmaxf(a.x, 0.0f), fmaxf(a.y, 0.0f)};
}

__global__ void __launch_bounds__(64)
__attribute__((amdgpu_waves_per_eu(1, 1)))
matchnet_kernel(
    const float* __restrict__ X,
    const float* __restrict__ W1, const float* __restrict__ b1,
    const float* __restrict__ W2, const float* __restrict__ b2,
    const float* __restrict__ W3, const float* __restrict__ b3,
    const float* __restrict__ W4, const float* __restrict__ b4,
    float* __restrict__ out, int B)
{
    __shared__ alignas(16) float sW1[120], sW2[400], sW3[400], sW4[160];
    __shared__ alignas(16) float sb1[20], sb2[20], sb3[20], sb4[8];
    {
        int tid = threadIdx.x;
        f4* dW1 = (f4*)sW1; const f4* gW1 = (const f4*)W1;
        for (int i = tid; i < 30; i += 64) dW1[i] = gW1[i];
        f4* dW2 = (f4*)sW2; const f4* gW2 = (const f4*)W2;
        for (int i = tid; i < 100; i += 64) dW2[i] = gW2[i];
        f4* dW3 = (f4*)sW3; const f4* gW3 = (const f4*)W3;
        for (int i = tid; i < 100; i += 64) dW3[i] = gW3[i];
        f4* dW4 = (f4*)sW4; const f4* gW4 = (const f4*)W4;
        for (int i = tid; i < 40; i += 64) dW4[i] = gW4[i];
        if (tid < 20) {
            sb1[tid] = b1[tid]; sb2[tid] = b2[tid]; sb3[tid] = b3[tid];
        }
        if (tid < 8) sb4[tid] = b4[tid];
    }
    __syncthreads();

    int row = blockIdx.x * blockDim.x + threadIdx.x;
    if (row >= B) return;

    // bids (= LP b vector), 3 aligned f2 loads
    const f2* xv = (const f2*)(X + row * 6);
    f2 bb01 = xv[0], bb23 = xv[1], bb45 = xv[2];
    float zin[6] = {bb01.x, bb01.y, bb23.x, bb23.y, bb45.x, bb45.y};

    // ---------------- MLP (packed pair-accumulators) ----------------
    float h[20];
    {
        f2 a[10];
        const f2* bv = (const f2*)sb1;
        #pragma unroll
        for (int p = 0; p < 10; p++) a[p] = bv[p];
        #pragma unroll
        for (int i = 0; i < 6; i++) {
            float v = zin[i];
            const f4* w = (const f4*)&sW1[i * 20];
            #pragma unroll
            for (int q = 0; q < 5; q++) {
                f4 ww = w[q];
                a[2 * q]     += v * f2{ww.x, ww.y};
                a[2 * q + 1] += v * f2{ww.z, ww.w};
            }
        }
        #pragma unroll
        for (int p = 0; p < 10; p++) {
            h[2 * p]     = fast_tanh(a[p].x);
            h[2 * p + 1] = fast_tanh(a[p].y);
        }
    }
    {
        f2 a[10];
        const f2* bv = (const f2*)sb2;
        #pragma unroll
        for (int p = 0; p < 10; p++) a[p] = bv[p];
        #pragma unroll
        for (int i = 0; i < 20; i++) {
            float v = h[i];
            const f4* w = (const f4*)&sW2[i * 20];
            #pragma unroll
            for (int q = 0; q < 5; q++) {
                f4 ww = w[q];
                a[2 * q]     += v * f2{ww.x, ww.y};
                a[2 * q + 1] += v * f2{ww.z, ww.w};
            }
        }
        #pragma unroll
        for (int p = 0; p < 10; p++) {
            h[2 * p]     = fast_tanh(a[p].x);
            h[2 * p + 1] = fast_tanh(a[p].y);
        }
    }
    {
        f2 a[10];
        const f2* bv = (const f2*)sb3;
        #pragma unroll
        for (int p = 0; p < 10; p++) a[p] = bv[p];
        #pragma unroll
        for (int i = 0; i < 20; i++) {
            float v = h[i];
            const f4* w = (const f4*)&sW3[i * 20];
            #pragma unroll
            for (int q = 0; q < 5; q++) {
                f4 ww = w[q];
                a[2 * q]     += v * f2{ww.x, ww.y};
                a[2 * q + 1] += v * f2{ww.z, ww.w};
            }
        }
        #pragma unroll
        for (int p = 0; p < 10; p++) {
            h[2 * p]     = fast_tanh(a[p].x);
            h[2 * p + 1] = fast_tanh(a[p].y);
        }
    }
    f2 z01, z23, z45, z67;
    {
        const f2* bv = (const f2*)sb4;
        f2 a0 = bv[0], a1 = bv[1], a2 = bv[2], a3 = bv[3];
        #pragma unroll
        for (int i = 0; i < 20; i++) {
            float v = h[i];
            const f4* w = (const f4*)&sW4[i * 8];
            f4 w0 = w[0], w1 = w[1];
            a0 += v * f2{w0.x, w0.y};
            a1 += v * f2{w0.z, w0.w};
            a2 += v * f2{w1.x, w1.y};
            a3 += v * f2{w1.z, w1.w};
        }
        z01 = a0; z23 = a1; z45 = a2; z67 = a3;
    }

    // ---------------- PDHG (packed) ----------------
    const float tau = 0.18898223650461363f;   // 1/sqrt(28)
    const float cc  = 0.03571428571428571f;   // tau*sigma = 1/28
    const float tauC = 1.8898223650461363f;   // tau*control_strength

    f2 t01 = tau - z01, t23 = tau - z23, t45 = tau - z45, t67 = tau - z67;
    float cb0 = cc * zin[0], cb1 = cc * zin[1], cb2 = cc * zin[2];
    float cb3 = cc * zin[3], cb4 = cc * zin[4], cb5 = cc * zin[5];

    f2 x01 = max0(z01), x23 = max0(z23), x45 = max0(z45), x67 = max0(z67);
    f2 xb01 = x01, xb23 = x23, xb45 = x45, xb67 = x67;
    f2 YI01 = {0.f, 0.f}, YI23 = {0.f, 0.f}, YI45 = {0.f, 0.f}, YI67 = {0.f, 0.f};
    float YS0 = 0.f, YS1 = 0.f, YS2 = 0.f, YS3 = 0.f, YS4 = 0.f, YS5 = 0.f;

    #pragma unroll 1
    for (int it = 0; it < N_ITERS; it++) {
        // dual I-rows (packed): YI = max(0, YI - c*xb)
        f2 u01 = YI01 - cc * xb01;
        f2 u23 = YI23 - cc * xb23;
        f2 u45 = YI45 - cc * xb45;
        f2 u67 = YI67 - cc * xb67;
        YI01 = max0(u01); YI23 = max0(u23); YI45 = max0(u45); YI67 = max0(u67);

        // dual S-rows (scalar; S sparsity hardcoded, p06 CSE)
        float p06 = xb01.x + xb67.x;
        float s0 = (xb01.x + xb23.x) + (xb45.y + xb67.y);
        float s1 = (xb01.y + xb23.y) + xb45.x;
        float s2 = p06 + xb01.y;
        float s3 = (xb23.x + xb23.y) + xb45.y;
        float s4 = (xb01.y + xb23.x) + (xb45.x + xb67.y);
        float s5 = p06 + xb45.x;
        float v0 = fmaf(cc, s0, YS0) - cb0;
        float v1 = fmaf(cc, s1, YS1) - cb1;
        float v2 = fmaf(cc, s2, YS2) - cb2;
        float v3 = fmaf(cc, s3, YS3) - cb3;
        float v4 = fmaf(cc, s4, YS4) - cb4;
        float v5 = fmaf(cc, s5, YS5) - cb5;
        YS0 = fmaxf(0.f, v0); YS1 = fmaxf(0.f, v1); YS2 = fmaxf(0.f, v2);
        YS3 = fmaxf(0.f, v3); YS4 = fmaxf(0.f, v4); YS5 = fmaxf(0.f, v5);

        // column sums (scalar, shared partials)
        float r03 = YS0 + YS3, r25 = YS2 + YS5, r14 = YS1 + YS4;
        f2 col01 = {YS0 + r25, r14 + YS2};
        f2 col23 = {r03 + YS4, YS1 + YS3};
        f2 col45 = {r14 + YS5, r03};
        f2 col67 = {r25, YS0 + YS4};

        // primal (packed): d = (x + t) + YI - col
        f2 e01 = x01 + t01, e23 = x23 + t23, e45 = x45 + t45, e67 = x67 + t67;
        f2 dA01 = e01 + YI01, dA23 = e23 + YI23, dA45 = e45 + YI45, dA67 = e67 + YI67;
        f2 d01 = dA01 - col01, d23 = dA23 - col23, d45 = dA45 - col45, d67 = dA67 - col67;

        // ||d||^2 (packed fma chain, then horizontal add)
        f2 m = d01 * d01;
        m += d23 * d23;
        m += d45 * d45;
        m += d67 * d67;
        float nsq = m.x + m.y;

        // scale = max(0, 1 - tauC/||d||); rsq(0)=inf -> 0 == ref clamp
        float rs = __builtin_amdgcn_rsqf(nsq);
        float scale = fmaxf(0.f, fmaf(-tauC, rs, 1.f));

        f2 xn01 = scale * d01 + z01;
        f2 xn23 = scale * d23 + z23;
        f2 xn45 = scale * d45 + z45;
        f2 xn67 = scale * d67 + z67;
        xb01 = 2.f * xn01 - x01; x01 = xn01;
        xb23 = 2.f * xn23 - x23; x23 = xn23;
        xb45 = 2.f * xn45 - x45; x45 = xn45;
        xb67 = 2.f * xn67 - x67; x67 = xn67;
    }

    f4* out4 = (f4*)out;
    out4[row * 2 + 0] = f4{x01.x, x01.y, x23.x, x23.y};
    out4[row * 2 + 1] = f4{x45.x, x45.y, x67.x, x67.y};
}

extern "C" void kernel_launch(void* const* d_in, const int* in_sizes, int n_in,
                              void* d_out, int out_size, void* d_ws, size_t ws_size,
                              hipStream_t stream) {
    const float* X  = (const float*)d_in[0];
    const float* W1 = (const float*)d_in[1];
    const float* b1 = (const float*)d_in[2];
    const float* W2 = (const float*)d_in[3];
    const float* b2 = (const float*)d_in[4];
    const float* W3 = (const float*)d_in[5];
    const float* b3 = (const float*)d_in[6];
    const float* W4 = (const float*)d_in[7];
    const float* b4 = (const float*)d_in[8];
    float* out = (float*)d_out;

    int B = in_sizes[0] / 6;
    const int block = 64;
    int grid = (B + block - 1) / block;
    hipLaunchKernelGGL(matchnet_kernel, dim3(grid), dim3(block), 0, stream,
                       X, W1, b1, W2, b2, W3, b3, W4, b4, out, B);
}